// Round 3
// baseline (303.969 us; speedup 1.0000x reference)
//
#include <hip/hip_runtime.h>
#include <math.h>

// Problem constants
#define DIM 64
#define KCB 512
#define NWIN 524288              // 16384 * 32 windows
#define ZQN (NWIN * DIM)         // 33554432
#define WPT 512                  // windows per tile (== threads per block in K1)
#define TPB 2                    // tiles per block
#define NBLK (NWIN / (WPT * TPB))  // 512 blocks = 2 per CU

typedef __attribute__((ext_vector_type(8))) short bf16x8;  // 8 bf16 = 4 VGPRs
typedef __attribute__((ext_vector_type(4))) float f32x4;

__device__ __forceinline__ unsigned bfbits(float f) { return __float_as_uint(f) >> 16; }

// pack 8 fp32 -> 8 bf16 (truncation; tolerance budget is enormous)
__device__ __forceinline__ int4 pack8(float4 a, float4 b) {
    int4 r;
    r.x = (int)(bfbits(a.x) | (__float_as_uint(a.y) & 0xffff0000u));
    r.y = (int)(bfbits(a.z) | (__float_as_uint(a.w) & 0xffff0000u));
    r.z = (int)(bfbits(b.x) | (__float_as_uint(b.y) & 0xffff0000u));
    r.w = (int)(bfbits(b.z) | (__float_as_uint(b.w) & 0xffff0000u));
    return r;
}

// ---------------------------------------------------------------------------
// K1: argmin + losses + histogram, v6 (de-fused, barrier-free main loop):
//  - v3's proven geometry: 512 threads, tt=4 (64 windows/wave/tile), TPB=2,
//    launch_bounds(512,4), 68 KiB LDS -> 2 blocks/CU.
//  - The zq gather phase moved to its own streaming kernel (K2). With it go
//    the per-tile __syncthreads and the LDS bank conflicts: the main loop has
//    ZERO barriers, so waves free-run and tile t+1's global loads (issued
//    right after the A-pack frees abuf) drain underneath the whole MFMA scan.
//    Rationale: v3/v4/v5 all ran at dur ~= hbm_bytes / 2.4 TB/s with
//    MfmaUtil+VALUBusy+mem ~ 65% non-overlapped -- phase-serialization, not
//    occupancy, was the limiter.
//  - score = 0.5||c||^2 - <z,c> entirely in MFMA (A = -z bf16, C = norms)
//  - epilogue: idx packed into low 9 mantissa bits + v_min3_f32
//  - owner lanes write idx directly to global (2 MB total, no idx_s/barrier)
// MFMA 16x16x32 bf16: A[m=lane&15][k=quad*8+j], B[k][n=lane&15],
// D: col(n)=lane&15, row(m)=quad*4+reg.
// ---------------------------------------------------------------------------
__global__ __launch_bounds__(512, 4) void vq_argmin_kernel(
    const float* __restrict__ ze, const float* __restrict__ cb,
    float* __restrict__ out_idx,
    int* __restrict__ counts, float* __restrict__ lossAcc)
{
    __shared__ int4  bfr[4096];     // 64 KiB: B frags [chunk32][h2][lane64]
    __shared__ float norm_s[KCB];   // 2 KiB HALVED row norms (0.5*||c||^2)
    __shared__ int   hist_s[KCB];   // 2 KiB histogram
    __shared__ float lpart[8];

    const int t    = threadIdx.x;   // 0..511
    const int lane = t & 63;
    const int wv   = t >> 6;        // wave 0..7
    const int q    = lane >> 4;
    const int l15  = lane & 15;
    const long blk = blockIdx.x;

    const float4* z4b = (const float4*)ze;

    // ---- issue tile 0's A loads first (no LDS dependency, drain under staging)
    float4 abuf[16];
    {
        const float4* z4 = z4b + blk * (long)(TPB * WPT * 16);
        const int m = wv * 64 + l15;
#pragma unroll
        for (int tt = 0; tt < 4; ++tt)
#pragma unroll
            for (int h = 0; h < 2; ++h)
#pragma unroll
                for (int i = 0; i < 2; ++i)
                    abuf[tt * 4 + h * 2 + i] = z4[(m + tt * 16) * 16 + h * 8 + q * 2 + i];
    }

    hist_s[t] = 0;

    // ---- halved codebook row norms (one row per thread)
    {
        const float4* c4 = (const float4*)cb;
        float s = 0.f;
#pragma unroll
        for (int i = 0; i < 16; ++i) {
            float4 v = c4[t * 16 + i];
            s += v.x * v.x + v.y * v.y + v.z * v.z + v.w * v.w;
        }
        norm_s[t] = 0.5f * s;
    }

    // ---- stage ALL 512 codes as B fragments (once per block)
#pragma unroll
    for (int i = 0; i < 8; ++i) {
        int f = i * 512 + t;
        int L = f & 63, rest = f >> 6, h = rest & 1, c = rest >> 1;  // c=0..31
        int n = c * 16 + (L & 15);
        int k = h * 32 + (L >> 4) * 8;
        const float4* s4 = (const float4*)(cb + n * DIM + k);
        bfr[(c * 2 + h) * 64 + L] = pack8(s4[0], s4[1]);
    }

    float lsum = 0.f;
    __syncthreads();   // bfr + norms visible; the ONLY barrier until the end

#pragma unroll
    for (int tl = 0; tl < TPB; ++tl) {
        const long g = blk * TPB + tl;

        // ---- pack current A to NEGATED bf16 frags + window norms
        bf16x8 afrag[4][2];
        float  znorm[4];
#pragma unroll
        for (int tt = 0; tt < 4; ++tt) {
            float part = 0.f;
#pragma unroll
            for (int h = 0; h < 2; ++h) {
                float4 a0 = abuf[tt * 4 + h * 2], a1 = abuf[tt * 4 + h * 2 + 1];
                part += a0.x*a0.x + a0.y*a0.y + a0.z*a0.z + a0.w*a0.w
                      + a1.x*a1.x + a1.y*a1.y + a1.z*a1.z + a1.w*a1.w;
                int4 p = pack8(a0, a1);
                p.x ^= 0x80008000; p.y ^= 0x80008000;   // negate both bf16 halves
                p.z ^= 0x80008000; p.w ^= 0x80008000;
                afrag[tt][h] = __builtin_bit_cast(bf16x8, p);
            }
            part += __shfl_xor(part, 16, 64);
            part += __shfl_xor(part, 32, 64);
            znorm[tt] = part;
        }

        // ---- abuf is dead now: issue NEXT tile's loads, drain under the scan
        if (tl < TPB - 1) {
            const float4* z4 = z4b + (g + 1) * (long)(WPT * 16);
            const int m = wv * 64 + l15;
#pragma unroll
            for (int tt = 0; tt < 4; ++tt)
#pragma unroll
                for (int h = 0; h < 2; ++h)
#pragma unroll
                    for (int i = 0; i < 2; ++i)
                        abuf[tt * 4 + h * 2 + i] = z4[(m + tt * 16) * 16 + h * 8 + q * 2 + i];
        }

        float best[4][4];
#pragma unroll
        for (int tt = 0; tt < 4; ++tt)
#pragma unroll
            for (int r = 0; r < 4; ++r) best[tt][r] = __uint_as_float(0x7e000000u);

        // ---- MFMA scan over 512 codes, 2 code-chunks per iteration
        for (int cp = 0; cp < 16; ++cp) {
            f32x4 e0[4], e1[4];
            {   // chunk c = 2*cp
                const int c = 2 * cp;
                bf16x8 b0 = __builtin_bit_cast(bf16x8, bfr[(c * 2 + 0) * 64 + lane]);
                bf16x8 b1 = __builtin_bit_cast(bf16x8, bfr[(c * 2 + 1) * 64 + lane]);
                float nh = norm_s[c * 16 + l15];
                f32x4 nrm4 = {nh, nh, nh, nh};
#pragma unroll
                for (int tt = 0; tt < 4; ++tt) {
                    e0[tt] = __builtin_amdgcn_mfma_f32_16x16x32_bf16(afrag[tt][0], b0, nrm4, 0, 0, 0);
                    e0[tt] = __builtin_amdgcn_mfma_f32_16x16x32_bf16(afrag[tt][1], b1, e0[tt], 0, 0, 0);
                }
            }
            {   // chunk c = 2*cp+1
                const int c = 2 * cp + 1;
                bf16x8 b0 = __builtin_bit_cast(bf16x8, bfr[(c * 2 + 0) * 64 + lane]);
                bf16x8 b1 = __builtin_bit_cast(bf16x8, bfr[(c * 2 + 1) * 64 + lane]);
                float nh = norm_s[c * 16 + l15];
                f32x4 nrm4 = {nh, nh, nh, nh};
#pragma unroll
                for (int tt = 0; tt < 4; ++tt) {
                    e1[tt] = __builtin_amdgcn_mfma_f32_16x16x32_bf16(afrag[tt][0], b0, nrm4, 0, 0, 0);
                    e1[tt] = __builtin_amdgcn_mfma_f32_16x16x32_bf16(afrag[tt][1], b1, e1[tt], 0, 0, 0);
                }
            }
            const unsigned n0 = (unsigned)(2 * cp) * 16 + (unsigned)l15;
            const unsigned n1 = n0 + 16;
#pragma unroll
            for (int tt = 0; tt < 4; ++tt)
#pragma unroll
                for (int r = 0; r < 4; ++r) {
                    float p0 = __uint_as_float((__float_as_uint(e0[tt][r]) & ~511u) | n0);
                    float p1 = __uint_as_float((__float_as_uint(e1[tt][r]) & ~511u) | n1);
                    best[tt][r] = fminf(fminf(best[tt][r], p0), p1);   // -> v_min3_f32
                }
        }

        // ---- min across the 16 lanes of each quad (n-direction)
#pragma unroll
        for (int tt = 0; tt < 4; ++tt)
#pragma unroll
            for (int r = 0; r < 4; ++r) {
                float v = best[tt][r];
                v = fminf(v, __shfl_xor(v, 1, 64));
                v = fminf(v, __shfl_xor(v, 2, 64));
                v = fminf(v, __shfl_xor(v, 4, 64));
                v = fminf(v, __shfl_xor(v, 8, 64));
                best[tt][r] = v;
            }

        // owner lanes (l15 == q*4+r, i.e. l15 == row m) write idx DIRECTLY to
        // global + record loss surrogate. r is compile-time (rule #20).
#pragma unroll
        for (int r = 0; r < 4; ++r) {
            if (l15 == q * 4 + r) {
#pragma unroll
                for (int tt = 0; tt < 4; ++tt) {
                    unsigned bb = __float_as_uint(best[tt][r]);
                    int   n  = (int)(bb & 511u);
                    float sc = __uint_as_float(bb & ~511u);
                    lsum += fmaf(2.f, sc, znorm[tt]);      // d^2 = ||z||^2 + 2*score
                    out_idx[g * WPT + wv * 64 + tt * 16 + l15] = (float)n;
                    atomicAdd(&hist_s[n], 1);
                }
            }
        }
        // no barrier: bfr/norm_s are read-only, hist_s is atomic
    }

    // ---- loss reduce + histogram flush
#pragma unroll
    for (int off = 32; off; off >>= 1) lsum += __shfl_down(lsum, off, 64);
    if (lane == 0) lpart[wv] = lsum;
    __syncthreads();   // orders hist_s atomics too
    if (t == 0) {
        float s = 0.f;
#pragma unroll
        for (int i = 0; i < 8; ++i) s += lpart[i];
        atomicAdd(lossAcc, s);
    }
    int h0 = hist_s[t];
    if (h0) atomicAdd(&counts[t], h0);
}

// ---------------------------------------------------------------------------
// K2: zq gather — pure streaming. idx read (2 MB, coalesced/broadcast),
// codebook gather from L2 (128 KB resident), coalesced fp32 stores (134 MB).
// 16 consecutive threads share one window -> stores are perfectly contiguous,
// cb row reads are 256 B contiguous per 16-lane group. Plain stores (v4
// showed nontemporal defeats L2/L3 write handling: +100 MB HBM traffic).
// ---------------------------------------------------------------------------
#define GELEMS (ZQN / 4)           // 8388608 float4 elements
#define K2BLK 2048
#define K2THR 256

__global__ __launch_bounds__(K2THR) void vq_gather_kernel(
    const float* __restrict__ idxf, const float* __restrict__ cb,
    float* __restrict__ zq)
{
    const f32x4* c4 = (const f32x4*)cb;
    f32x4*       z4 = (f32x4*)zq;
    long i = (long)blockIdx.x * K2THR + threadIdx.x;
    const long stride = (long)K2BLK * K2THR;   // 524288 -> exactly 16 iters
#pragma unroll 4
    for (; i < GELEMS; i += stride) {
        long w = i >> 4;
        int  j = (int)(i & 15);
        int  n = (int)idxf[w];
        z4[i] = c4[n * 16 + j];
    }
}

// ---------------------------------------------------------------------------
// Finalize: entropy from counts + loss scalars
// ---------------------------------------------------------------------------
__global__ __launch_bounds__(512) void vq_finalize_kernel(
    const int* __restrict__ counts, const float* __restrict__ lossAcc,
    float* __restrict__ outs)
{
    __shared__ float partial[8];
    const int t = threadIdx.x;

    float p = (float)counts[t] * 0.1f;
    float term = p * logf(p + 1e-10f);
#pragma unroll
    for (int off = 32; off; off >>= 1) term += __shfl_down(term, off, 64);
    if ((t & 63) == 0) partial[t >> 6] = term;
    __syncthreads();
    if (t == 0) {
        float e = 0.f;
#pragma unroll
        for (int i = 0; i < 8; ++i) e += partial[i];
        float loss = lossAcc[0] / (float)ZQN;
        outs[0] = loss;
        outs[1] = loss;
        outs[2] = e;
    }
}

extern "C" void kernel_launch(void* const* d_in, const int* in_sizes, int n_in,
                              void* d_out, int out_size, void* d_ws, size_t ws_size,
                              hipStream_t stream) {
    const float* ze = (const float*)d_in[0];   // [16384, 2048] fp32
    const float* cb = (const float*)d_in[1];   // [512, 64] fp32
    float* out = (float*)d_out;

    // d_out layout: [idx: NWIN | zq: ZQN | vq_e | vq_commit | entropy]
    float* out_idx = out;
    float* out_zq  = out + NWIN;
    float* out_scl = out + NWIN + (long)ZQN;

    int*   counts  = (int*)d_ws;
    float* lossAcc = (float*)((char*)d_ws + KCB * sizeof(int));
    hipMemsetAsync(d_ws, 0, KCB * sizeof(int) + sizeof(float), stream);

    vq_argmin_kernel<<<NBLK, 512, 0, stream>>>(ze, cb, out_idx, counts, lossAcc);
    vq_gather_kernel<<<K2BLK, K2THR, 0, stream>>>(out_idx, cb, out_zq);
    vq_finalize_kernel<<<1, KCB, 0, stream>>>(counts, lossAcc, out_scl);
}

// Round 4
// 276.890 us; speedup vs baseline: 1.0978x; 1.0978x over previous
//
#include <hip/hip_runtime.h>
#include <math.h>

// Problem constants
#define DIM 64
#define KCB 512
#define NWIN 524288              // 16384 * 32 windows
#define ZQN (NWIN * DIM)         // 33554432
#define WPT 256                  // windows per tile (== threads per block in K1)
#define TPB 4                    // tiles per block
#define NBLK (NWIN / (WPT * TPB))  // 512 blocks = 2 per CU

typedef __attribute__((ext_vector_type(8))) short bf16x8;  // 8 bf16 = 4 VGPRs
typedef __attribute__((ext_vector_type(4))) float f32x4;

__device__ __forceinline__ unsigned bfbits(float f) { return __float_as_uint(f) >> 16; }

// pack 8 fp32 -> 8 bf16 (truncation; tolerance budget is enormous)
__device__ __forceinline__ int4 pack8(float4 a, float4 b) {
    int4 r;
    r.x = (int)(bfbits(a.x) | (__float_as_uint(a.y) & 0xffff0000u));
    r.y = (int)(bfbits(a.z) | (__float_as_uint(a.w) & 0xffff0000u));
    r.z = (int)(bfbits(b.x) | (__float_as_uint(b.y) & 0xffff0000u));
    r.w = (int)(bfbits(b.z) | (__float_as_uint(b.w) & 0xffff0000u));
    return r;
}

// ---------------------------------------------------------------------------
// K1: argmin + losses + histogram, v7 (register-starvation fix):
//  - v6 post-mortem: K1 alone == fused v3 (112 us) at 12% MfmaUtil, VALU
//    cycles 3-4x the algorithmic need, VGPR_Count=64. launch_bounds(512,4)
//    capped waves at 128 unified regs -> compiler ping-pongs state through
//    AGPRs (accvgpr read/write = the excess VALU) and can't pipeline the
//    per-chunk LDS b-frag reads (raw lgkmcnt stall every chunk).
//  - Fix: trade TLP for registers. 256-thread blocks, launch_bounds(256,2),
//    TPB=4 -> still 512 blocks, 2 blocks/CU (144 KB LDS), 2 waves/SIMD,
//    but 256 unified VGPRs/wave. Same math, same per-wave tile (tt=4),
//    barrier-free main loop, next-tile A prefetch in regs (now affordable).
//  - idx via LDS + one coalesced float4/thread flush at the end (v6's
//    scattered 4B owner stores amplified 2 MB -> 53 MB of HBM writes).
// MFMA 16x16x32 bf16: A[m=lane&15][k=quad*8+j], B[k][n=lane&15],
// D: col(n)=lane&15, row(m)=quad*4+reg.
// ---------------------------------------------------------------------------
__global__ __launch_bounds__(256, 2) void vq_argmin_kernel(
    const float* __restrict__ ze, const float* __restrict__ cb,
    float* __restrict__ out_idx,
    int* __restrict__ counts, float* __restrict__ lossAcc)
{
    __shared__ int4  bfr[4096];        // 64 KiB: B frags [chunk32][h2][lane64]
    __shared__ float norm_s[KCB];      // 2 KiB HALVED row norms (0.5*||c||^2)
    __shared__ int   hist_s[KCB];      // 2 KiB histogram
    __shared__ int   idx_all[TPB][WPT];// 4 KiB all tiles' argmin
    __shared__ float lpart[4];

    const int t    = threadIdx.x;   // 0..255
    const int lane = t & 63;
    const int wv   = t >> 6;        // wave 0..3
    const int q    = lane >> 4;
    const int l15  = lane & 15;
    const long blk = blockIdx.x;

    const float4* z4b = (const float4*)ze;

    // ---- issue tile 0's A loads first (no LDS dependency, drain under staging)
    float4 abuf[16];
    {
        const float4* z4 = z4b + blk * (long)(TPB * WPT * 16);
        const int m = wv * 64 + l15;
#pragma unroll
        for (int tt = 0; tt < 4; ++tt)
#pragma unroll
            for (int h = 0; h < 2; ++h)
#pragma unroll
                for (int i = 0; i < 2; ++i)
                    abuf[tt * 4 + h * 2 + i] = z4[(m + tt * 16) * 16 + h * 8 + q * 2 + i];
    }

    hist_s[t] = 0;
    hist_s[t + 256] = 0;

    // ---- halved codebook row norms (two rows per thread)
    {
        const float4* c4 = (const float4*)cb;
#pragma unroll
        for (int rr = 0; rr < 2; ++rr) {
            int row = rr * 256 + t;
            float s = 0.f;
#pragma unroll
            for (int i = 0; i < 16; ++i) {
                float4 v = c4[row * 16 + i];
                s += v.x * v.x + v.y * v.y + v.z * v.z + v.w * v.w;
            }
            norm_s[row] = 0.5f * s;
        }
    }

    // ---- stage ALL 512 codes as B fragments (once per block)
#pragma unroll
    for (int i = 0; i < 16; ++i) {
        int f = i * 256 + t;
        int L = f & 63, rest = f >> 6, h = rest & 1, c = rest >> 1;  // c=0..31
        int n = c * 16 + (L & 15);
        int k = h * 32 + (L >> 4) * 8;
        const float4* s4 = (const float4*)(cb + n * DIM + k);
        bfr[(c * 2 + h) * 64 + L] = pack8(s4[0], s4[1]);
    }

    float lsum = 0.f;
    __syncthreads();   // bfr + norms visible; the ONLY barrier until the end

#pragma unroll
    for (int tl = 0; tl < TPB; ++tl) {
        const long g = blk * TPB + tl;

        // ---- pack current A to NEGATED bf16 frags + window norms
        bf16x8 afrag[4][2];
        float  znorm[4];
#pragma unroll
        for (int tt = 0; tt < 4; ++tt) {
            float part = 0.f;
#pragma unroll
            for (int h = 0; h < 2; ++h) {
                float4 a0 = abuf[tt * 4 + h * 2], a1 = abuf[tt * 4 + h * 2 + 1];
                part += a0.x*a0.x + a0.y*a0.y + a0.z*a0.z + a0.w*a0.w
                      + a1.x*a1.x + a1.y*a1.y + a1.z*a1.z + a1.w*a1.w;
                int4 p = pack8(a0, a1);
                p.x ^= 0x80008000; p.y ^= 0x80008000;   // negate both bf16 halves
                p.z ^= 0x80008000; p.w ^= 0x80008000;
                afrag[tt][h] = __builtin_bit_cast(bf16x8, p);
            }
            part += __shfl_xor(part, 16, 64);
            part += __shfl_xor(part, 32, 64);
            znorm[tt] = part;
        }

        // ---- abuf is dead now: issue NEXT tile's loads, drain under the scan
        if (tl < TPB - 1) {
            const float4* z4 = z4b + (g + 1) * (long)(WPT * 16);
            const int m = wv * 64 + l15;
#pragma unroll
            for (int tt = 0; tt < 4; ++tt)
#pragma unroll
                for (int h = 0; h < 2; ++h)
#pragma unroll
                    for (int i = 0; i < 2; ++i)
                        abuf[tt * 4 + h * 2 + i] = z4[(m + tt * 16) * 16 + h * 8 + q * 2 + i];
        }

        float best[4][4];
#pragma unroll
        for (int tt = 0; tt < 4; ++tt)
#pragma unroll
            for (int r = 0; r < 4; ++r) best[tt][r] = __uint_as_float(0x7e000000u);

        // ---- MFMA scan over 512 codes, 2 code-chunks per iteration
        for (int cp = 0; cp < 16; ++cp) {
            f32x4 e0[4], e1[4];
            {   // chunk c = 2*cp
                const int c = 2 * cp;
                bf16x8 b0 = __builtin_bit_cast(bf16x8, bfr[(c * 2 + 0) * 64 + lane]);
                bf16x8 b1 = __builtin_bit_cast(bf16x8, bfr[(c * 2 + 1) * 64 + lane]);
                float nh = norm_s[c * 16 + l15];
                f32x4 nrm4 = {nh, nh, nh, nh};
#pragma unroll
                for (int tt = 0; tt < 4; ++tt) {
                    e0[tt] = __builtin_amdgcn_mfma_f32_16x16x32_bf16(afrag[tt][0], b0, nrm4, 0, 0, 0);
                    e0[tt] = __builtin_amdgcn_mfma_f32_16x16x32_bf16(afrag[tt][1], b1, e0[tt], 0, 0, 0);
                }
            }
            {   // chunk c = 2*cp+1
                const int c = 2 * cp + 1;
                bf16x8 b0 = __builtin_bit_cast(bf16x8, bfr[(c * 2 + 0) * 64 + lane]);
                bf16x8 b1 = __builtin_bit_cast(bf16x8, bfr[(c * 2 + 1) * 64 + lane]);
                float nh = norm_s[c * 16 + l15];
                f32x4 nrm4 = {nh, nh, nh, nh};
#pragma unroll
                for (int tt = 0; tt < 4; ++tt) {
                    e1[tt] = __builtin_amdgcn_mfma_f32_16x16x32_bf16(afrag[tt][0], b0, nrm4, 0, 0, 0);
                    e1[tt] = __builtin_amdgcn_mfma_f32_16x16x32_bf16(afrag[tt][1], b1, e1[tt], 0, 0, 0);
                }
            }
            const unsigned n0 = (unsigned)(2 * cp) * 16 + (unsigned)l15;
            const unsigned n1 = n0 + 16;
#pragma unroll
            for (int tt = 0; tt < 4; ++tt)
#pragma unroll
                for (int r = 0; r < 4; ++r) {
                    float p0 = __uint_as_float((__float_as_uint(e0[tt][r]) & ~511u) | n0);
                    float p1 = __uint_as_float((__float_as_uint(e1[tt][r]) & ~511u) | n1);
                    best[tt][r] = fminf(fminf(best[tt][r], p0), p1);   // -> v_min3_f32
                }
        }

        // ---- min across the 16 lanes of each quad (n-direction)
#pragma unroll
        for (int tt = 0; tt < 4; ++tt)
#pragma unroll
            for (int r = 0; r < 4; ++r) {
                float v = best[tt][r];
                v = fminf(v, __shfl_xor(v, 1, 64));
                v = fminf(v, __shfl_xor(v, 2, 64));
                v = fminf(v, __shfl_xor(v, 4, 64));
                v = fminf(v, __shfl_xor(v, 8, 64));
                best[tt][r] = v;
            }

        // owner lanes (l15 == q*4+r) record idx (to LDS) + loss surrogate.
        // r is compile-time (rule #20: no runtime-indexed register arrays).
#pragma unroll
        for (int r = 0; r < 4; ++r) {
            if (l15 == q * 4 + r) {
#pragma unroll
                for (int tt = 0; tt < 4; ++tt) {
                    unsigned bb = __float_as_uint(best[tt][r]);
                    int   n  = (int)(bb & 511u);
                    float sc = __uint_as_float(bb & ~511u);
                    lsum += fmaf(2.f, sc, znorm[tt]);      // d^2 = ||z||^2 + 2*score
                    idx_all[tl][wv * 64 + tt * 16 + l15] = n;
                    atomicAdd(&hist_s[n], 1);
                }
            }
        }
        // no barrier: bfr/norm_s read-only, idx_all slot private to this tile
    }

    __syncthreads();   // idx_all + hist atomics complete

    // ---- coalesced idx flush: block's TPB*WPT = 1024 idx are contiguous.
    // thread t converts 4 consecutive entries -> one float4 store.
    {
        int f0 = t * 4;                    // 0..1023, all 4 in same tile row
        int tl = f0 >> 8, w = f0 & 255;
        float4 o;
        o.x = (float)idx_all[tl][w + 0];
        o.y = (float)idx_all[tl][w + 1];
        o.z = (float)idx_all[tl][w + 2];
        o.w = (float)idx_all[tl][w + 3];
        ((float4*)(out_idx + blk * (long)(TPB * WPT)))[t] = o;
    }

    // ---- loss reduce + histogram flush
#pragma unroll
    for (int off = 32; off; off >>= 1) lsum += __shfl_down(lsum, off, 64);
    if (lane == 0) lpart[wv] = lsum;
    __syncthreads();
    if (t == 0) {
        float s = 0.f;
#pragma unroll
        for (int i = 0; i < 4; ++i) s += lpart[i];
        atomicAdd(lossAcc, s);
    }
    {
        int h0 = hist_s[t];
        if (h0) atomicAdd(&counts[t], h0);
        int h1 = hist_s[t + 256];
        if (h1) atomicAdd(&counts[t + 256], h1);
    }
}

// ---------------------------------------------------------------------------
// K2: zq gather — pure streaming. idx read (2 MB, coalesced/broadcast),
// codebook gather from L2 (128 KB resident), coalesced fp32 stores (134 MB).
// 16 consecutive threads share one window -> stores are perfectly contiguous.
// Plain stores (v4 showed nontemporal defeats L2/L3 write handling).
// ---------------------------------------------------------------------------
#define GELEMS (ZQN / 4)           // 8388608 float4 elements
#define K2BLK 2048
#define K2THR 256

__global__ __launch_bounds__(K2THR) void vq_gather_kernel(
    const float* __restrict__ idxf, const float* __restrict__ cb,
    float* __restrict__ zq)
{
    const f32x4* c4 = (const f32x4*)cb;
    f32x4*       z4 = (f32x4*)zq;
    long i = (long)blockIdx.x * K2THR + threadIdx.x;
    const long stride = (long)K2BLK * K2THR;   // 524288 -> exactly 16 iters
#pragma unroll 4
    for (; i < GELEMS; i += stride) {
        long w = i >> 4;
        int  j = (int)(i & 15);
        int  n = (int)idxf[w];
        z4[i] = c4[n * 16 + j];
    }
}

// ---------------------------------------------------------------------------
// Finalize: entropy from counts + loss scalars
// ---------------------------------------------------------------------------
__global__ __launch_bounds__(512) void vq_finalize_kernel(
    const int* __restrict__ counts, const float* __restrict__ lossAcc,
    float* __restrict__ outs)
{
    __shared__ float partial[8];
    const int t = threadIdx.x;

    float p = (float)counts[t] * 0.1f;
    float term = p * logf(p + 1e-10f);
#pragma unroll
    for (int off = 32; off; off >>= 1) term += __shfl_down(term, off, 64);
    if ((t & 63) == 0) partial[t >> 6] = term;
    __syncthreads();
    if (t == 0) {
        float e = 0.f;
#pragma unroll
        for (int i = 0; i < 8; ++i) e += partial[i];
        float loss = lossAcc[0] / (float)ZQN;
        outs[0] = loss;
        outs[1] = loss;
        outs[2] = e;
    }
}

extern "C" void kernel_launch(void* const* d_in, const int* in_sizes, int n_in,
                              void* d_out, int out_size, void* d_ws, size_t ws_size,
                              hipStream_t stream) {
    const float* ze = (const float*)d_in[0];   // [16384, 2048] fp32
    const float* cb = (const float*)d_in[1];   // [512, 64] fp32
    float* out = (float*)d_out;

    // d_out layout: [idx: NWIN | zq: ZQN | vq_e | vq_commit | entropy]
    float* out_idx = out;
    float* out_zq  = out + NWIN;
    float* out_scl = out + NWIN + (long)ZQN;

    int*   counts  = (int*)d_ws;
    float* lossAcc = (float*)((char*)d_ws + KCB * sizeof(int));
    hipMemsetAsync(d_ws, 0, KCB * sizeof(int) + sizeof(float), stream);

    vq_argmin_kernel<<<NBLK, 256, 0, stream>>>(ze, cb, out_idx, counts, lossAcc);
    vq_gather_kernel<<<K2BLK, K2THR, 0, stream>>>(out_idx, cb, out_zq);
    vq_finalize_kernel<<<1, KCB, 0, stream>>>(counts, lossAcc, out_scl);
}

// Round 5
// 271.922 us; speedup vs baseline: 1.1179x; 1.0183x over previous
//
#include <hip/hip_runtime.h>
#include <math.h>

// Problem constants
#define DIM 64
#define KCB 512
#define NWIN 524288              // 16384 * 32 windows
#define ZQN (NWIN * DIM)         // 33554432
#define WPT 512                  // windows per tile (== threads per block in K1)
#define TPB 2                    // tiles per block
#define NBLK (NWIN / (WPT * TPB))  // 512 blocks = 2 per CU

typedef __attribute__((ext_vector_type(8))) short bf16x8;  // 8 bf16 = 4 VGPRs
typedef __attribute__((ext_vector_type(4))) float f32x4;

__device__ __forceinline__ unsigned bfbits(float f) { return __float_as_uint(f) >> 16; }

// pack 8 fp32 -> 8 bf16 (truncation; tolerance budget is enormous)
__device__ __forceinline__ int4 pack8(float4 a, float4 b) {
    int4 r;
    r.x = (int)(bfbits(a.x) | (__float_as_uint(a.y) & 0xffff0000u));
    r.y = (int)(bfbits(a.z) | (__float_as_uint(a.w) & 0xffff0000u));
    r.z = (int)(bfbits(b.x) | (__float_as_uint(b.y) & 0xffff0000u));
    r.w = (int)(bfbits(b.z) | (__float_as_uint(b.w) & 0xffff0000u));
    return r;
}

// ---------------------------------------------------------------------------
// K1: argmin + losses + histogram, v8 (occupancy x codegen stack):
//  - v7 post-mortem with corrected counter units: VALUBusy 35% is CU-level
//    (~9%/SIMD) and matches the algorithmic VALU count -- VALU was never the
//    limiter. At 84 us: MFMA pipe 16% fed, HBM 10%, everything idle =>
//    latency-bound at 2 waves/SIMD. v6 showed 4 waves/SIMD with AGPR-churn
//    codegen ~= 2 waves/SIMD with clean codegen (after removing its 28-us
//    scattered-idx-store poison). v8 stacks both:
//      * 512-thr blocks, launch_bounds(512,4), TPB=2 -> 512 blocks,
//        2 blocks/CU (144 KB LDS), 16 waves/CU = 4 waves/SIMD.
//      * NO register A-prefetch (v6/v7's abuf = 64 VGPRs): live set ~90 regs
//        fits the 128-reg cap without AGPR parking; 4-way wave TLP covers
//        the tile-head load latency instead.
//      * coalesced idx flush via LDS (v7's fix, keeps WRITE at ~3 MB).
//  - score = 0.5||c||^2 - <z,c> entirely in MFMA (A = -z bf16, C = norms)
//  - epilogue: idx packed into low 9 mantissa bits + v_min3_f32
// MFMA 16x16x32 bf16: A[m=lane&15][k=quad*8+j], B[k][n=lane&15],
// D: col(n)=lane&15, row(m)=quad*4+reg.
// ---------------------------------------------------------------------------
__global__ __launch_bounds__(512, 4) void vq_argmin_kernel(
    const float* __restrict__ ze, const float* __restrict__ cb,
    float* __restrict__ out_idx,
    int* __restrict__ counts, float* __restrict__ lossAcc)
{
    __shared__ int4  bfr[4096];        // 64 KiB: B frags [chunk32][h2][lane64]
    __shared__ float norm_s[KCB];      // 2 KiB HALVED row norms (0.5*||c||^2)
    __shared__ int   hist_s[KCB];      // 2 KiB histogram
    __shared__ int   idx_all[TPB][WPT];// 4 KiB all tiles' argmin
    __shared__ float lpart[8];

    const int t    = threadIdx.x;   // 0..511
    const int lane = t & 63;
    const int wv   = t >> 6;        // wave 0..7
    const int q    = lane >> 4;
    const int l15  = lane & 15;
    const long blk = blockIdx.x;

    const float4* z4b = (const float4*)ze;

    hist_s[t] = 0;

    // ---- halved codebook row norms (one row per thread)
    {
        const float4* c4 = (const float4*)cb;
        float s = 0.f;
#pragma unroll
        for (int i = 0; i < 16; ++i) {
            float4 v = c4[t * 16 + i];
            s += v.x * v.x + v.y * v.y + v.z * v.z + v.w * v.w;
        }
        norm_s[t] = 0.5f * s;
    }

    // ---- stage ALL 512 codes as B fragments (once per block)
#pragma unroll
    for (int i = 0; i < 8; ++i) {
        int f = i * 512 + t;
        int L = f & 63, rest = f >> 6, h = rest & 1, c = rest >> 1;  // c=0..31
        int n = c * 16 + (L & 15);
        int k = h * 32 + (L >> 4) * 8;
        const float4* s4 = (const float4*)(cb + n * DIM + k);
        bfr[(c * 2 + h) * 64 + L] = pack8(s4[0], s4[1]);
    }

    float lsum = 0.f;
    __syncthreads();   // bfr + norms visible; the ONLY barrier until the end

#pragma unroll
    for (int tl = 0; tl < TPB; ++tl) {
        const long g = blk * TPB + tl;
        const float4* z4 = z4b + g * (long)(WPT * 16);
        const int m = wv * 64 + l15;   // + tt*16 below

        // ---- load + pack A to NEGATED bf16 frags + window norms
        // (no persistent prefetch buffer: 4 waves/SIMD TLP hides the latency)
        bf16x8 afrag[4][2];
        float  znorm[4];
#pragma unroll
        for (int tt = 0; tt < 4; ++tt) {
            float part = 0.f;
#pragma unroll
            for (int h = 0; h < 2; ++h) {
                float4 a0 = z4[(m + tt * 16) * 16 + h * 8 + q * 2 + 0];
                float4 a1 = z4[(m + tt * 16) * 16 + h * 8 + q * 2 + 1];
                part += a0.x*a0.x + a0.y*a0.y + a0.z*a0.z + a0.w*a0.w
                      + a1.x*a1.x + a1.y*a1.y + a1.z*a1.z + a1.w*a1.w;
                int4 p = pack8(a0, a1);
                p.x ^= 0x80008000; p.y ^= 0x80008000;   // negate both bf16 halves
                p.z ^= 0x80008000; p.w ^= 0x80008000;
                afrag[tt][h] = __builtin_bit_cast(bf16x8, p);
            }
            part += __shfl_xor(part, 16, 64);
            part += __shfl_xor(part, 32, 64);
            znorm[tt] = part;
        }

        float best[4][4];
#pragma unroll
        for (int tt = 0; tt < 4; ++tt)
#pragma unroll
            for (int r = 0; r < 4; ++r) best[tt][r] = __uint_as_float(0x7e000000u);

        // ---- MFMA scan over 512 codes, 2 code-chunks per iteration
        for (int cp = 0; cp < 16; ++cp) {
            f32x4 e0[4], e1[4];
            {   // chunk c = 2*cp
                const int c = 2 * cp;
                bf16x8 b0 = __builtin_bit_cast(bf16x8, bfr[(c * 2 + 0) * 64 + lane]);
                bf16x8 b1 = __builtin_bit_cast(bf16x8, bfr[(c * 2 + 1) * 64 + lane]);
                float nh = norm_s[c * 16 + l15];
                f32x4 nrm4 = {nh, nh, nh, nh};
#pragma unroll
                for (int tt = 0; tt < 4; ++tt) {
                    e0[tt] = __builtin_amdgcn_mfma_f32_16x16x32_bf16(afrag[tt][0], b0, nrm4, 0, 0, 0);
                    e0[tt] = __builtin_amdgcn_mfma_f32_16x16x32_bf16(afrag[tt][1], b1, e0[tt], 0, 0, 0);
                }
            }
            {   // chunk c = 2*cp+1
                const int c = 2 * cp + 1;
                bf16x8 b0 = __builtin_bit_cast(bf16x8, bfr[(c * 2 + 0) * 64 + lane]);
                bf16x8 b1 = __builtin_bit_cast(bf16x8, bfr[(c * 2 + 1) * 64 + lane]);
                float nh = norm_s[c * 16 + l15];
                f32x4 nrm4 = {nh, nh, nh, nh};
#pragma unroll
                for (int tt = 0; tt < 4; ++tt) {
                    e1[tt] = __builtin_amdgcn_mfma_f32_16x16x32_bf16(afrag[tt][0], b0, nrm4, 0, 0, 0);
                    e1[tt] = __builtin_amdgcn_mfma_f32_16x16x32_bf16(afrag[tt][1], b1, e1[tt], 0, 0, 0);
                }
            }
            const unsigned n0 = (unsigned)(2 * cp) * 16 + (unsigned)l15;
            const unsigned n1 = n0 + 16;
#pragma unroll
            for (int tt = 0; tt < 4; ++tt)
#pragma unroll
                for (int r = 0; r < 4; ++r) {
                    float p0 = __uint_as_float((__float_as_uint(e0[tt][r]) & ~511u) | n0);
                    float p1 = __uint_as_float((__float_as_uint(e1[tt][r]) & ~511u) | n1);
                    best[tt][r] = fminf(fminf(best[tt][r], p0), p1);   // -> v_min3_f32
                }
        }

        // ---- min across the 16 lanes of each quad (n-direction)
#pragma unroll
        for (int tt = 0; tt < 4; ++tt)
#pragma unroll
            for (int r = 0; r < 4; ++r) {
                float v = best[tt][r];
                v = fminf(v, __shfl_xor(v, 1, 64));
                v = fminf(v, __shfl_xor(v, 2, 64));
                v = fminf(v, __shfl_xor(v, 4, 64));
                v = fminf(v, __shfl_xor(v, 8, 64));
                best[tt][r] = v;
            }

        // owner lanes (l15 == q*4+r) record idx (to LDS) + loss surrogate.
        // r is compile-time (rule #20: no runtime-indexed register arrays).
#pragma unroll
        for (int r = 0; r < 4; ++r) {
            if (l15 == q * 4 + r) {
#pragma unroll
                for (int tt = 0; tt < 4; ++tt) {
                    unsigned bb = __float_as_uint(best[tt][r]);
                    int   n  = (int)(bb & 511u);
                    float sc = __uint_as_float(bb & ~511u);
                    lsum += fmaf(2.f, sc, znorm[tt]);      // d^2 = ||z||^2 + 2*score
                    idx_all[tl][wv * 64 + tt * 16 + l15] = n;
                    atomicAdd(&hist_s[n], 1);
                }
            }
        }
        // no barrier: bfr/norm_s read-only, idx_all slot private to this tile
    }

    __syncthreads();   // idx_all + hist atomics complete

    // ---- coalesced idx flush: block's TPB*WPT = 1024 idx are contiguous.
    // thread t < 256 converts 4 consecutive entries -> one float4 store.
    if (t < 256) {
        int f0 = t * 4;                    // 0..1023, all 4 in same tile row
        int tl = f0 >> 9, w = f0 & 511;
        float4 o;
        o.x = (float)idx_all[tl][w + 0];
        o.y = (float)idx_all[tl][w + 1];
        o.z = (float)idx_all[tl][w + 2];
        o.w = (float)idx_all[tl][w + 3];
        ((float4*)(out_idx + blk * (long)(TPB * WPT)))[t] = o;
    }

    // ---- loss reduce + histogram flush
#pragma unroll
    for (int off = 32; off; off >>= 1) lsum += __shfl_down(lsum, off, 64);
    if (lane == 0) lpart[wv] = lsum;
    __syncthreads();
    if (t == 0) {
        float s = 0.f;
#pragma unroll
        for (int i = 0; i < 8; ++i) s += lpart[i];
        atomicAdd(lossAcc, s);
    }
    {
        int h0 = hist_s[t];
        if (h0) atomicAdd(&counts[t], h0);
    }
}

// ---------------------------------------------------------------------------
// K2: zq gather — pure streaming. idx read (2 MB, coalesced/broadcast),
// codebook gather from L2 (128 KB resident), coalesced fp32 stores (134 MB).
// 16 consecutive threads share one window -> stores are perfectly contiguous.
// Plain stores (v4 showed nontemporal defeats L2/L3 write handling).
// ---------------------------------------------------------------------------
#define GELEMS (ZQN / 4)           // 8388608 float4 elements
#define K2BLK 2048
#define K2THR 256

__global__ __launch_bounds__(K2THR) void vq_gather_kernel(
    const float* __restrict__ idxf, const float* __restrict__ cb,
    float* __restrict__ zq)
{
    const f32x4* c4 = (const f32x4*)cb;
    f32x4*       z4 = (f32x4*)zq;
    long i = (long)blockIdx.x * K2THR + threadIdx.x;
    const long stride = (long)K2BLK * K2THR;   // 524288 -> exactly 16 iters
#pragma unroll 4
    for (; i < GELEMS; i += stride) {
        long w = i >> 4;
        int  j = (int)(i & 15);
        int  n = (int)idxf[w];
        z4[i] = c4[n * 16 + j];
    }
}

// ---------------------------------------------------------------------------
// Finalize: entropy from counts + loss scalars
// ---------------------------------------------------------------------------
__global__ __launch_bounds__(512) void vq_finalize_kernel(
    const int* __restrict__ counts, const float* __restrict__ lossAcc,
    float* __restrict__ outs)
{
    __shared__ float partial[8];
    const int t = threadIdx.x;

    float p = (float)counts[t] * 0.1f;
    float term = p * logf(p + 1e-10f);
#pragma unroll
    for (int off = 32; off; off >>= 1) term += __shfl_down(term, off, 64);
    if ((t & 63) == 0) partial[t >> 6] = term;
    __syncthreads();
    if (t == 0) {
        float e = 0.f;
#pragma unroll
        for (int i = 0; i < 8; ++i) e += partial[i];
        float loss = lossAcc[0] / (float)ZQN;
        outs[0] = loss;
        outs[1] = loss;
        outs[2] = e;
    }
}

extern "C" void kernel_launch(void* const* d_in, const int* in_sizes, int n_in,
                              void* d_out, int out_size, void* d_ws, size_t ws_size,
                              hipStream_t stream) {
    const float* ze = (const float*)d_in[0];   // [16384, 2048] fp32
    const float* cb = (const float*)d_in[1];   // [512, 64] fp32
    float* out = (float*)d_out;

    // d_out layout: [idx: NWIN | zq: ZQN | vq_e | vq_commit | entropy]
    float* out_idx = out;
    float* out_zq  = out + NWIN;
    float* out_scl = out + NWIN + (long)ZQN;

    int*   counts  = (int*)d_ws;
    float* lossAcc = (float*)((char*)d_ws + KCB * sizeof(int));
    hipMemsetAsync(d_ws, 0, KCB * sizeof(int) + sizeof(float), stream);

    vq_argmin_kernel<<<NBLK, 512, 0, stream>>>(ze, cb, out_idx, counts, lossAcc);
    vq_gather_kernel<<<K2BLK, K2THR, 0, stream>>>(out_idx, cb, out_zq);
    vq_finalize_kernel<<<1, KCB, 0, stream>>>(counts, lossAcc, out_scl);
}

// Round 6
// 269.511 us; speedup vs baseline: 1.1279x; 1.0089x over previous
//
#include <hip/hip_runtime.h>
#include <math.h>

// Problem constants
#define DIM 64
#define KCB 512
#define NWIN 524288              // 16384 * 32 windows
#define ZQN (NWIN * DIM)         // 33554432
#define WPT 512                  // windows per block (== threads per block)
#define NBLK (NWIN / WPT)        // 1024 blocks = 4 per CU lifetime, 2 resident

typedef __attribute__((ext_vector_type(8))) short bf16x8;  // 8 bf16 = 4 VGPRs
typedef __attribute__((ext_vector_type(4))) float f32x4;

__device__ __forceinline__ unsigned bfbits(float f) { return __float_as_uint(f) >> 16; }

// pack 8 fp32 -> 8 bf16 (truncation; tolerance budget is enormous)
__device__ __forceinline__ int4 pack8(float4 a, float4 b) {
    int4 r;
    r.x = (int)(bfbits(a.x) | (__float_as_uint(a.y) & 0xffff0000u));
    r.y = (int)(bfbits(a.z) | (__float_as_uint(a.w) & 0xffff0000u));
    r.z = (int)(bfbits(b.x) | (__float_as_uint(b.y) & 0xffff0000u));
    r.w = (int)(bfbits(b.z) | (__float_as_uint(b.w) & 0xffff0000u));
    return r;
}

// ---------------------------------------------------------------------------
// Fused VQ kernel, v9 (phase-decorrelation):
//  v8 post-mortem: occupancy 2x (17->33%) gave only 84->80.6 us => NOT
//  TLP-limited. Issue-cost audit: ~11 us of issue vs 80 us wall = 85% stall;
//  K1 HBM at 880 GB/s. The tile-synchronized [load-burst | scan] phases
//  serialize HBM and MFMA chip-wide (all waves hit each phase in lockstep).
//  v9 restructures for phase overlap WITHOUT persistent prefetch registers:
//   - TPB=1, 1024 blocks: block turnover decorrelates phases across the 2
//     co-resident blocks/CU (4 blocks/CU over the kernel lifetime).
//   - A-tile loads are issued as the FIRST instructions of the block; their
//     ~1-2 us of HBM latency drains under the cb->bfr staging phase and the
//     pre-scan barrier instead of serializing in front of the scan.
//   - zq gather re-fused (v3's proven LDS-gather epilogue): removes the
//     separate 35-us K2; the write burst overlaps other blocks' reads/scans.
//  score = 0.5||c||^2 - <z,c> entirely in MFMA (A = -z bf16, C = norms);
//  epilogue: idx packed into low 9 mantissa bits + v_min3_f32.
// MFMA 16x16x32 bf16: A[m=lane&15][k=quad*8+j], B[k][n=lane&15],
// D: col(n)=lane&15, row(m)=quad*4+reg.
// ---------------------------------------------------------------------------
__global__ __launch_bounds__(512, 4) void vq_fused_kernel(
    const float* __restrict__ ze, const float* __restrict__ cb,
    float* __restrict__ out_idx, float* __restrict__ zq,
    int* __restrict__ counts, float* __restrict__ lossAcc)
{
    __shared__ int4  bfr[4096];     // 64 KiB: B frags [chunk32][h2][lane64]
    __shared__ float norm_s[KCB];   // 2 KiB HALVED row norms (0.5*||c||^2)
    __shared__ int   hist_s[KCB];   // 2 KiB histogram
    __shared__ int   idx_s[WPT];    // 2 KiB per-window argmin
    __shared__ float lpart[8];

    const int t    = threadIdx.x;   // 0..511
    const int lane = t & 63;
    const int wv   = t >> 6;        // wave 0..7
    const int q    = lane >> 4;
    const int l15  = lane & 15;
    const long blk = blockIdx.x;

    const float4* z4b = (const float4*)ze;

    // ---- FIRST: issue this block's A-tile loads. Latency drains under the
    // staging below + the barrier. Transient regs only (dead after pack).
    float4 ld[16];
    {
        const float4* z4 = z4b + blk * (long)(WPT * 16);
        const int m = wv * 64 + l15;
#pragma unroll
        for (int tt = 0; tt < 4; ++tt)
#pragma unroll
            for (int h = 0; h < 2; ++h)
#pragma unroll
                for (int i = 0; i < 2; ++i)
                    ld[tt * 4 + h * 2 + i] = z4[(m + tt * 16) * 16 + h * 8 + q * 2 + i];
    }

    hist_s[t] = 0;

    // ---- halved codebook row norms (one row per thread)
    {
        const float4* c4 = (const float4*)cb;
        float s = 0.f;
#pragma unroll
        for (int i = 0; i < 16; ++i) {
            float4 v = c4[t * 16 + i];
            s += v.x * v.x + v.y * v.y + v.z * v.z + v.w * v.w;
        }
        norm_s[t] = 0.5f * s;
    }

    // ---- stage ALL 512 codes as B fragments
#pragma unroll
    for (int i = 0; i < 8; ++i) {
        int f = i * 512 + t;
        int L = f & 63, rest = f >> 6, h = rest & 1, c = rest >> 1;  // c=0..31
        int n = c * 16 + (L & 15);
        int k = h * 32 + (L >> 4) * 8;
        const float4* s4 = (const float4*)(cb + n * DIM + k);
        bfr[(c * 2 + h) * 64 + L] = pack8(s4[0], s4[1]);
    }

    __syncthreads();   // bfr + norms visible; also drains the A loads

    // ---- pack A to NEGATED bf16 frags + window norms (data already here)
    bf16x8 afrag[4][2];
    float  znorm[4];
#pragma unroll
    for (int tt = 0; tt < 4; ++tt) {
        float part = 0.f;
#pragma unroll
        for (int h = 0; h < 2; ++h) {
            float4 a0 = ld[tt * 4 + h * 2], a1 = ld[tt * 4 + h * 2 + 1];
            part += a0.x*a0.x + a0.y*a0.y + a0.z*a0.z + a0.w*a0.w
                  + a1.x*a1.x + a1.y*a1.y + a1.z*a1.z + a1.w*a1.w;
            int4 p = pack8(a0, a1);
            p.x ^= 0x80008000; p.y ^= 0x80008000;   // negate both bf16 halves
            p.z ^= 0x80008000; p.w ^= 0x80008000;
            afrag[tt][h] = __builtin_bit_cast(bf16x8, p);
        }
        part += __shfl_xor(part, 16, 64);
        part += __shfl_xor(part, 32, 64);
        znorm[tt] = part;
    }

    float best[4][4];
#pragma unroll
    for (int tt = 0; tt < 4; ++tt)
#pragma unroll
        for (int r = 0; r < 4; ++r) best[tt][r] = __uint_as_float(0x7e000000u);

    // ---- MFMA scan over 512 codes, 2 code-chunks per iteration
    for (int cp = 0; cp < 16; ++cp) {
        f32x4 e0[4], e1[4];
        {   // chunk c = 2*cp
            const int c = 2 * cp;
            bf16x8 b0 = __builtin_bit_cast(bf16x8, bfr[(c * 2 + 0) * 64 + lane]);
            bf16x8 b1 = __builtin_bit_cast(bf16x8, bfr[(c * 2 + 1) * 64 + lane]);
            float nh = norm_s[c * 16 + l15];
            f32x4 nrm4 = {nh, nh, nh, nh};
#pragma unroll
            for (int tt = 0; tt < 4; ++tt) {
                e0[tt] = __builtin_amdgcn_mfma_f32_16x16x32_bf16(afrag[tt][0], b0, nrm4, 0, 0, 0);
                e0[tt] = __builtin_amdgcn_mfma_f32_16x16x32_bf16(afrag[tt][1], b1, e0[tt], 0, 0, 0);
            }
        }
        {   // chunk c = 2*cp+1
            const int c = 2 * cp + 1;
            bf16x8 b0 = __builtin_bit_cast(bf16x8, bfr[(c * 2 + 0) * 64 + lane]);
            bf16x8 b1 = __builtin_bit_cast(bf16x8, bfr[(c * 2 + 1) * 64 + lane]);
            float nh = norm_s[c * 16 + l15];
            f32x4 nrm4 = {nh, nh, nh, nh};
#pragma unroll
            for (int tt = 0; tt < 4; ++tt) {
                e1[tt] = __builtin_amdgcn_mfma_f32_16x16x32_bf16(afrag[tt][0], b0, nrm4, 0, 0, 0);
                e1[tt] = __builtin_amdgcn_mfma_f32_16x16x32_bf16(afrag[tt][1], b1, e1[tt], 0, 0, 0);
            }
        }
        const unsigned n0 = (unsigned)(2 * cp) * 16 + (unsigned)l15;
        const unsigned n1 = n0 + 16;
#pragma unroll
        for (int tt = 0; tt < 4; ++tt)
#pragma unroll
            for (int r = 0; r < 4; ++r) {
                float p0 = __uint_as_float((__float_as_uint(e0[tt][r]) & ~511u) | n0);
                float p1 = __uint_as_float((__float_as_uint(e1[tt][r]) & ~511u) | n1);
                best[tt][r] = fminf(fminf(best[tt][r], p0), p1);   // -> v_min3_f32
            }
    }

    // ---- min across the 16 lanes of each quad (n-direction)
#pragma unroll
    for (int tt = 0; tt < 4; ++tt)
#pragma unroll
        for (int r = 0; r < 4; ++r) {
            float v = best[tt][r];
            v = fminf(v, __shfl_xor(v, 1, 64));
            v = fminf(v, __shfl_xor(v, 2, 64));
            v = fminf(v, __shfl_xor(v, 4, 64));
            v = fminf(v, __shfl_xor(v, 8, 64));
            best[tt][r] = v;
        }

    // owner lanes (l15 == q*4+r) record idx (to LDS) + loss surrogate.
    // r is compile-time (rule #20: no runtime-indexed register arrays).
    float lsum = 0.f;
#pragma unroll
    for (int r = 0; r < 4; ++r) {
        if (l15 == q * 4 + r) {
#pragma unroll
            for (int tt = 0; tt < 4; ++tt) {
                unsigned bb = __float_as_uint(best[tt][r]);
                int   n  = (int)(bb & 511u);
                float sc = __uint_as_float(bb & ~511u);
                lsum += fmaf(2.f, sc, znorm[tt]);      // d^2 = ||z||^2 + 2*score
                idx_s[wv * 64 + tt * 16 + l15] = n;
                atomicAdd(&hist_s[n], 1);
            }
        }
    }

    __syncthreads();   // idx_s complete

    // ---- coalesced index write
    out_idx[blk * (long)WPT + t] = (float)idx_s[t];

    // ---- zq gather straight from LDS frags (bf16 -> fp32), plain stores
    {
        float4* zq4 = (float4*)zq;
        const long zb = blk * (long)(WPT * 16);   // float4 units
#pragma unroll
        for (int it = 0; it < 16; ++it) {
            int w_loc = it * 32 + (t >> 4);
            int j  = t & 15;            // float4 index in window
            int n  = idx_s[w_loc];
            int c  = n >> 4, ln = n & 15;
            int h  = j >> 3;
            int q2 = (j >> 1) & 3;
            int4 v = bfr[(c * 2 + h) * 64 + q2 * 16 + ln];
            int a  = (j & 1) ? v.z : v.x;
            int b  = (j & 1) ? v.w : v.y;
            float4 o;
            o.x = __uint_as_float((unsigned)a << 16);
            o.y = __uint_as_float((unsigned)a & 0xffff0000u);
            o.z = __uint_as_float((unsigned)b << 16);
            o.w = __uint_as_float((unsigned)b & 0xffff0000u);
            zq4[zb + (long)w_loc * 16 + j] = o;
        }
    }

    // ---- loss reduce + histogram flush
#pragma unroll
    for (int off = 32; off; off >>= 1) lsum += __shfl_down(lsum, off, 64);
    if (lane == 0) lpart[wv] = lsum;
    __syncthreads();   // lpart visible; hist atomics already ordered above
    if (t == 0) {
        float s = 0.f;
#pragma unroll
        for (int i = 0; i < 8; ++i) s += lpart[i];
        atomicAdd(lossAcc, s);
    }
    {
        int h0 = hist_s[t];
        if (h0) atomicAdd(&counts[t], h0);
    }
}

// ---------------------------------------------------------------------------
// Finalize: entropy from counts + loss scalars
// ---------------------------------------------------------------------------
__global__ __launch_bounds__(512) void vq_finalize_kernel(
    const int* __restrict__ counts, const float* __restrict__ lossAcc,
    float* __restrict__ outs)
{
    __shared__ float partial[8];
    const int t = threadIdx.x;

    float p = (float)counts[t] * 0.1f;
    float term = p * logf(p + 1e-10f);
#pragma unroll
    for (int off = 32; off; off >>= 1) term += __shfl_down(term, off, 64);
    if ((t & 63) == 0) partial[t >> 6] = term;
    __syncthreads();
    if (t == 0) {
        float e = 0.f;
#pragma unroll
        for (int i = 0; i < 8; ++i) e += partial[i];
        float loss = lossAcc[0] / (float)ZQN;
        outs[0] = loss;
        outs[1] = loss;
        outs[2] = e;
    }
}

extern "C" void kernel_launch(void* const* d_in, const int* in_sizes, int n_in,
                              void* d_out, int out_size, void* d_ws, size_t ws_size,
                              hipStream_t stream) {
    const float* ze = (const float*)d_in[0];   // [16384, 2048] fp32
    const float* cb = (const float*)d_in[1];   // [512, 64] fp32
    float* out = (float*)d_out;

    // d_out layout: [idx: NWIN | zq: ZQN | vq_e | vq_commit | entropy]
    float* out_idx = out;
    float* out_zq  = out + NWIN;
    float* out_scl = out + NWIN + (long)ZQN;

    int*   counts  = (int*)d_ws;
    float* lossAcc = (float*)((char*)d_ws + KCB * sizeof(int));
    hipMemsetAsync(d_ws, 0, KCB * sizeof(int) + sizeof(float), stream);

    vq_fused_kernel<<<NBLK, 512, 0, stream>>>(ze, cb, out_idx, out_zq, counts, lossAcc);
    vq_finalize_kernel<<<1, KCB, 0, stream>>>(counts, lossAcc, out_scl);
}